// Round 2
// baseline (563.620 us; speedup 1.0000x reference)
//
#include <hip/hip_runtime.h>
#include <math.h>

#define NN 64
#define HH 128
#define LL 4

// WT layout (bf16 elements, per layer)
#define OFF_CW2T 0
#define OFF_W1AT 16384
#define OFF_W1BT 32768
#define OFF_W1CT 49152
#define OFF_EW2T 65536
#define OFF_NW2T 81920
#define OFF_NW1T 98304
#define WT_LAYER 131072

typedef short s8v __attribute__((ext_vector_type(8)));
typedef float f4v __attribute__((ext_vector_type(4)));

__device__ __forceinline__ short f2bf(float f){
  unsigned u = __float_as_uint(f);
  u += 0x7fffu + ((u>>16)&1u);
  return (short)(u>>16);
}
__device__ __forceinline__ float bf2f(short s){
  return __uint_as_float(((unsigned)(unsigned short)s)<<16);
}
__device__ __forceinline__ float gelu(float x){
  return 0.5f*x*(1.0f + erff(x*0.70710678118654752f));
}
__device__ __forceinline__ f4v mfma16(s8v a, s8v b, f4v c){
  return __builtin_amdgcn_mfma_f32_16x16x32_bf16(a,b,c,0,0,0);
}

// ---------------- kernel 0: transpose+convert all weights to bf16 [N][K] ----
__global__ __launch_bounds__(256) void k_wt(
  const float* __restrict__ cW2, const float* __restrict__ eW1,
  const float* __restrict__ eW2, const float* __restrict__ nW1,
  const float* __restrict__ nW2, short* __restrict__ WT)
{
  int gid = blockIdx.x*256 + threadIdx.x;   // 0 .. 524287
  int l = gid >> 17;
  int r = gid & 131071;
  float v;
  if (r < 32768 && r >= 16384){          // w1at
    int i = r-16384; int n = i>>7, k = i&127;
    v = eW1[l*49152 + k*128 + n];
  } else if (r < 16384){                 // cw2t
    int n = r>>7, k = r&127;
    v = cW2[l*16384 + k*128 + n];
  } else if (r < 49152){                 // w1bt
    int i = r-32768; int n = i>>7, k = i&127;
    v = eW1[l*49152 + (128+k)*128 + n];
  } else if (r < 65536){                 // w1ct
    int i = r-49152; int n = i>>7, k = i&127;
    v = eW1[l*49152 + (256+k)*128 + n];
  } else if (r < 81920){                 // ew2t
    int i = r-65536; int n = i>>7, k = i&127;
    v = eW2[l*16384 + k*128 + n];
  } else if (r < 98304){                 // nw2t
    int i = r-81920; int n = i>>7, k = i&127;
    v = nW2[l*16384 + k*128 + n];
  } else {                               // nw1t [128][256]
    int i = r-98304; int n = i>>8, k = i&255;
    v = nW1[l*32768 + k*128 + n];
  }
  WT[gid] = f2bf(v);
}

// ---------------- kernel 1: LayerNorm + AB precompute GEMM ------------------
// AB[node][0:128]  = hn @ eW1[0:128]   (A-term, fp32)
// AB[node][128:256]= hn @ eW1[128:256] (B-term, fp32)
__global__ __launch_bounds__(256) void k_ln_ab(
    const float* __restrict__ h,
    const float* __restrict__ lng, const float* __restrict__ lnb,
    const short* __restrict__ WT,
    float* __restrict__ hnf, float* __restrict__ ABf)
{
  __shared__ __align__(16) short hl[16*128];
  const int t = threadIdx.x;
  const int nl = t>>4, l16 = t&15;
  const int gn = blockIdx.x*16 + nl;
  const float* hp = h + gn*128 + l16*8;
  float4 f0 = *(const float4*)hp;
  float4 f1 = *(const float4*)(hp+4);
  float x[8] = {f0.x,f0.y,f0.z,f0.w,f1.x,f1.y,f1.z,f1.w};
  float s=0.f, sq=0.f;
  #pragma unroll
  for (int i=0;i<8;i++){ s += x[i]; sq += x[i]*x[i]; }
  #pragma unroll
  for (int m=1;m<16;m<<=1){ s += __shfl_xor(s,m,64); sq += __shfl_xor(sq,m,64); }
  float mu = s*(1.f/128.f);
  float var = sq*(1.f/128.f) - mu*mu;
  float rstd = rsqrtf(var + 1e-5f);
  s8v pk;
  float y[8];
  #pragma unroll
  for (int i=0;i<8;i++){
    int k = l16*8+i;
    y[i] = (x[i]-mu)*rstd*lng[k] + lnb[k];
    pk[i] = f2bf(y[i]);
  }
  float4 o0; o0.x=y[0];o0.y=y[1];o0.z=y[2];o0.w=y[3];
  float4 o1; o1.x=y[4];o1.y=y[5];o1.z=y[6];o1.w=y[7];
  *(float4*)(hnf + gn*128 + l16*8)     = o0;
  *(float4*)(hnf + gn*128 + l16*8 + 4) = o1;
  *(s8v*)&hl[nl*128 + ((l16 ^ (nl&7))<<3)] = pk;
  __syncthreads();

  const int w = t>>6, lane = t&63, q = lane>>4, c16 = lane&15;
  f4v acc[4];
  #pragma unroll
  for (int j=0;j<4;j++){
    #pragma unroll
    for (int e=0;e<4;e++) acc[j][e] = 0.f;
  }
  #pragma unroll
  for (int s4=0;s4<4;s4++){
    int kc = 4*s4+q;
    s8v a = *(const s8v*)&hl[c16*128 + ((kc ^ (c16&7))<<3)];
    #pragma unroll
    for (int j=0;j<4;j++){
      int cn = (w*4+j)*16 + c16;              // 0..255
      const short* bp = (cn < 128) ? (WT + OFF_W1AT + cn*128)
                                   : (WT + OFF_W1BT + (cn-128)*128);
      s8v bb = *(const s8v*)(bp + kc*8);
      acc[j] = mfma16(a, bb, acc[j]);
    }
  }
  #pragma unroll
  for (int j=0;j<4;j++){
    int cn = (w*4+j)*16 + c16;
    #pragma unroll
    for (int r=0;r<4;r++){
      ABf[(blockIdx.x*16 + 4*q + r)*256 + cn] = acc[j][r];
    }
  }
}

// ---------------- kernel 2: fused edge pipeline + aggregation ---------------
// One WG = (graph b, 8 rows). Loops 8 chunks of 8 cols; per chunk M=64 edges.
// cd1 -> GEMM(cW2) -> GEMM(W1c)+A+B -> GEMM(eW2) -> masked sum_j into agg.
__global__ __launch_bounds__(256) void k_edge(
    const float* __restrict__ coord,
    const float* __restrict__ cW1l,
    const float* __restrict__ cb1g, const float* __restrict__ cb2g,
    const float* __restrict__ eb1g, const float* __restrict__ eb2g,
    const short* __restrict__ WT,
    const float* __restrict__ ABf,
    float* __restrict__ agg)
{
  __shared__ __align__(16) short Wc[2*128*128]; // [0]=cw2t [16384]=ew2t (swizzled)
  __shared__ __align__(16) short t0[64*128];
  __shared__ __align__(16) short t1[64*128];
  __shared__ __align__(16) float Atf[8*128];
  __shared__ __align__(16) float Btf[64*128];
  __shared__ __align__(16) float aggl[8*128];
  __shared__ float w1x[128], w1y[128], b1s[128], b2s[128], e1s[128], e2s[128];
  __shared__ float cxr[8], cyr[8], cxj[64], cyj[64];

  const int t = threadIdx.x;
  const int b  = blockIdx.x >> 3;
  const int rb = blockIdx.x & 7;
  const int gbase = b*NN;
  const int rows0 = gbase + rb*8;

  // stage swizzled weight matrices (cw2t, ew2t)
  #pragma unroll
  for (int i=0;i<8;i++){
    int idx16 = t + i*256;
    int n = idx16>>4, c = idx16&15;
    int dsw = n*128 + ((c ^ (n&7))<<3);
    *(s8v*)&Wc[dsw]          = *(const s8v*)(WT + OFF_CW2T + n*128 + c*8);
    *(s8v*)&Wc[16384 + dsw]  = *(const s8v*)(WT + OFF_EW2T + n*128 + c*8);
  }
  if (t < 128){
    w1x[t] = cW1l[t]; w1y[t] = cW1l[128+t];
    b1s[t] = cb1g[t]; b2s[t] = cb2g[t];
    e1s[t] = eb1g[t]; e2s[t] = eb2g[t];
  }
  if (t < 64){ cxj[t] = coord[(gbase+t)*2]; cyj[t] = coord[(gbase+t)*2+1]; }
  if (t >= 64 && t < 72){ int r=t-64; cxr[r] = coord[(rows0+r)*2]; cyr[r] = coord[(rows0+r)*2+1]; }
  // A-term rows (fp32)
  { int r = t>>5, c = t&31;
    *(float4*)&Atf[r*128 + c*4] = *(const float4*)(ABf + (rows0+r)*256 + c*4); }
  // B-term cols (fp32) + zero agg
  #pragma unroll
  for (int i=0;i<8;i++){
    int idx4 = t + i*256;            // 0..2047 float4 chunks
    int j = idx4>>5, c = idx4&31;
    *(float4*)&Btf[j*128 + c*4] = *(const float4*)(ABf + (gbase+j)*256 + 128 + c*4);
  }
  #pragma unroll
  for (int i=0;i<4;i++) aggl[t + i*256] = 0.f;

  const int w = t>>6, lane = t&63, q = lane>>4, c16 = lane&15;
  const int mtb = (w>>1)*2;      // m-tiles {mtb, mtb+1}
  const int ntb = (w&1)*4;       // n-tiles ntb..ntb+3

  // GEMM2 (W1c) B-fragments in registers, straight from global (linear)
  s8v wreg[4][4];
  #pragma unroll
  for (int j=0;j<4;j++){
    int n = (ntb+j)*16 + c16;
    #pragma unroll
    for (int s=0;s<4;s++)
      wreg[j][s] = *(const s8v*)(WT + OFF_W1CT + n*128 + (4*s+q)*8);
  }
  __syncthreads();

  const int row0 = mtb*16 + c16;
  const int row1 = row0 + 16;
  const int swz  = row0 & 7;     // row1&7 == row0&7

  for (int ch=0; ch<8; ch++){
    const int j0 = ch*8;
    // ---- Phase A: cd1 -> t0 ----
    {
      int m = t & 63;
      int r = m>>3, jj = m&7;
      float dx = cxr[r] - cxj[j0+jj];
      float dy = cyr[r] - cyj[j0+jj];
      int cb = t>>6;
      #pragma unroll
      for (int s=0;s<4;s++){
        int kc = cb + s*4;
        s8v pk;
        #pragma unroll
        for (int kk=0;kk<8;kk++){
          int k = kc*8+kk;
          pk[kk] = f2bf(gelu(fmaf(dx, w1x[k], fmaf(dy, w1y[k], b1s[k]))));
        }
        *(s8v*)&t0[m*128 + ((kc ^ (m&7))<<3)] = pk;
      }
    }
    __syncthreads();
    // ---- Phase B: t1 = gelu(t0 @ cW2 + cb2) ----
    {
      f4v a0c[4], a1c[4];
      #pragma unroll
      for (int j=0;j<4;j++){
        #pragma unroll
        for (int e=0;e<4;e++){ a0c[j][e]=0.f; a1c[j][e]=0.f; }
      }
      #pragma unroll
      for (int s=0;s<4;s++){
        int kc = 4*s+q;
        s8v a0 = *(const s8v*)&t0[row0*128 + ((kc ^ swz)<<3)];
        s8v a1 = *(const s8v*)&t0[row1*128 + ((kc ^ swz)<<3)];
        #pragma unroll
        for (int j=0;j<4;j++){
          int n = (ntb+j)*16 + c16;
          s8v bb = *(const s8v*)&Wc[n*128 + ((kc ^ (n&7))<<3)];
          a0c[j] = mfma16(a0, bb, a0c[j]);
          a1c[j] = mfma16(a1, bb, a1c[j]);
        }
      }
      #pragma unroll
      for (int mi=0;mi<2;mi++){
        #pragma unroll
        for (int j=0;j<4;j++){
          int cn = (ntb+j)*16 + c16;
          #pragma unroll
          for (int r=0;r<4;r++){
            int m = (mtb+mi)*16 + 4*q + r;
            float v = (mi==0 ? a0c[j][r] : a1c[j][r]) + b2s[cn];
            t1[m*128 + (((cn>>3) ^ (m&7))<<3) + (cn&7)] = f2bf(gelu(v));
          }
        }
      }
    }
    __syncthreads();
    // ---- Phase C: t0 = gelu(t1 @ W1c + A[i] + B[j] + eb1) ----
    {
      f4v a0c[4], a1c[4];
      #pragma unroll
      for (int j=0;j<4;j++){
        #pragma unroll
        for (int e=0;e<4;e++){ a0c[j][e]=0.f; a1c[j][e]=0.f; }
      }
      #pragma unroll
      for (int s=0;s<4;s++){
        int kc = 4*s+q;
        s8v a0 = *(const s8v*)&t1[row0*128 + ((kc ^ swz)<<3)];
        s8v a1 = *(const s8v*)&t1[row1*128 + ((kc ^ swz)<<3)];
        #pragma unroll
        for (int j=0;j<4;j++){
          a0c[j] = mfma16(a0, wreg[j][s], a0c[j]);
          a1c[j] = mfma16(a1, wreg[j][s], a1c[j]);
        }
      }
      #pragma unroll
      for (int mi=0;mi<2;mi++){
        #pragma unroll
        for (int j=0;j<4;j++){
          int cn = (ntb+j)*16 + c16;
          #pragma unroll
          for (int r=0;r<4;r++){
            int m = (mtb+mi)*16 + 4*q + r;
            int rr = m>>3, jj = m&7;
            float v = (mi==0 ? a0c[j][r] : a1c[j][r])
                    + Atf[rr*128+cn] + Btf[(j0+jj)*128+cn] + e1s[cn];
            t0[m*128 + (((cn>>3) ^ (m&7))<<3) + (cn&7)] = f2bf(gelu(v));
          }
        }
      }
    }
    __syncthreads();
    // ---- Phase D: ef2 = gelu(t0 @ eW2 + eb2); masked sum_j -> aggl ----
    {
      f4v a0c[4], a1c[4];
      #pragma unroll
      for (int j=0;j<4;j++){
        #pragma unroll
        for (int e=0;e<4;e++){ a0c[j][e]=0.f; a1c[j][e]=0.f; }
      }
      #pragma unroll
      for (int s=0;s<4;s++){
        int kc = 4*s+q;
        s8v a0 = *(const s8v*)&t0[row0*128 + ((kc ^ swz)<<3)];
        s8v a1 = *(const s8v*)&t0[row1*128 + ((kc ^ swz)<<3)];
        #pragma unroll
        for (int j=0;j<4;j++){
          int n = (ntb+j)*16 + c16;
          s8v bb = *(const s8v*)&Wc[16384 + n*128 + ((kc ^ (n&7))<<3)];
          a0c[j] = mfma16(a0, bb, a0c[j]);
          a1c[j] = mfma16(a1, bb, a1c[j]);
        }
      }
      #pragma unroll
      for (int mi=0;mi<2;mi++){
        #pragma unroll
        for (int j=0;j<4;j++){
          int cn = (ntb+j)*16 + c16;
          float s = 0.f;
          #pragma unroll
          for (int r=0;r<4;r++){
            int m = (mtb+mi)*16 + 4*q + r;
            float g = gelu((mi==0 ? a0c[j][r] : a1c[j][r]) + e2s[cn]);
            int rr = m>>3, jj = m&7;
            if (rb*8 + rr == j0 + jj) g = 0.f;   // no self-loop
            s += g;
          }
          s += __shfl_xor(s, 16, 64);
          if ((q&1)==0)
            aggl[(2*(mtb+mi) + (q>>1))*128 + cn] += s;
        }
      }
    }
    __syncthreads();
  }
  #pragma unroll
  for (int i=0;i<4;i++){
    int idx = t + i*256;
    agg[(rows0 + (idx>>7))*128 + (idx&127)] = aggl[idx];
  }
}

// ---------------- kernel 3: node MLP + residual -----------------------------
__global__ __launch_bounds__(256) void k_node(
    const float* __restrict__ hnf, const float* __restrict__ aggg,
    const float* __restrict__ nb1l, const float* __restrict__ nb2l,
    const short* __restrict__ WT,
    float* __restrict__ hout)
{
  __shared__ __align__(16) short cat[16*256];
  __shared__ __align__(16) short u1[16*128];
  __shared__ __align__(16) float hf[16*128];
  const int t = threadIdx.x;
  {
    const int row = t>>4, c = t&15;
    const int gn = blockIdx.x*16 + row;
    float4 f0 = *(const float4*)(hnf + gn*128 + c*8);
    float4 f1 = *(const float4*)(hnf + gn*128 + c*8 + 4);
    *(float4*)&hf[row*128 + c*8]     = f0;
    *(float4*)&hf[row*128 + c*8 + 4] = f1;
    s8v p;
    p[0]=f2bf(f0.x);p[1]=f2bf(f0.y);p[2]=f2bf(f0.z);p[3]=f2bf(f0.w);
    p[4]=f2bf(f1.x);p[5]=f2bf(f1.y);p[6]=f2bf(f1.z);p[7]=f2bf(f1.w);
    *(s8v*)&cat[row*256 + ((c ^ (row&7))<<3)] = p;
    float4 g0 = *(const float4*)(aggg + gn*128 + c*8);
    float4 g1 = *(const float4*)(aggg + gn*128 + c*8 + 4);
    s8v pg;
    pg[0]=f2bf(g0.x);pg[1]=f2bf(g0.y);pg[2]=f2bf(g0.z);pg[3]=f2bf(g0.w);
    pg[4]=f2bf(g1.x);pg[5]=f2bf(g1.y);pg[6]=f2bf(g1.z);pg[7]=f2bf(g1.w);
    *(s8v*)&cat[row*256 + (((16+c) ^ (row&7))<<3)] = pg;
  }
  __syncthreads();
  const int w = t>>6, lane = t&63, q = lane>>4, c16 = lane&15;
  f4v acc[2];
  #pragma unroll
  for (int j=0;j<2;j++){
    #pragma unroll
    for (int e=0;e<4;e++) acc[j][e]=0.f;
  }
  #pragma unroll
  for (int s=0;s<8;s++){
    int kc = 4*s+q;                           // 0..31
    s8v a = *(const s8v*)&cat[c16*256 + ((kc ^ (c16&7))<<3)];
    #pragma unroll
    for (int j=0;j<2;j++){
      int cn = (w*2+j)*16 + c16;
      s8v bb = *(const s8v*)(WT + OFF_NW1T + cn*256 + kc*8);
      acc[j] = mfma16(a, bb, acc[j]);
    }
  }
  #pragma unroll
  for (int j=0;j<2;j++){
    int cn = (w*2+j)*16 + c16;
    #pragma unroll
    for (int r=0;r<4;r++){
      int m = 4*q+r;
      float v = acc[j][r] + nb1l[cn];
      u1[m*128 + (((cn>>3) ^ (m&7))<<3) + (cn&7)] = f2bf(gelu(v));
    }
  }
  __syncthreads();
  f4v acc2[2];
  #pragma unroll
  for (int j=0;j<2;j++){
    #pragma unroll
    for (int e=0;e<4;e++) acc2[j][e]=0.f;
  }
  #pragma unroll
  for (int s=0;s<4;s++){
    int kc = 4*s+q;
    s8v a = *(const s8v*)&u1[c16*128 + ((kc ^ (c16&7))<<3)];
    #pragma unroll
    for (int j=0;j<2;j++){
      int cn = (w*2+j)*16 + c16;
      s8v bb = *(const s8v*)(WT + OFF_NW2T + cn*128 + kc*8);
      acc2[j] = mfma16(a, bb, acc2[j]);
    }
  }
  #pragma unroll
  for (int j=0;j<2;j++){
    int cn = (w*2+j)*16 + c16;
    #pragma unroll
    for (int r=0;r<4;r++){
      int m = 4*q+r;
      hout[(blockIdx.x*16 + m)*128 + cn] = hf[m*128 + cn] + acc2[j][r] + nb2l[cn];
    }
  }
}

// ---------------- launch ----------------------------------------------------
extern "C" void kernel_launch(void* const* d_in, const int* in_sizes, int n_in,
                              void* d_out, int out_size, void* d_ws, size_t ws_size,
                              hipStream_t stream)
{
  (void)in_sizes; (void)n_in; (void)out_size; (void)ws_size;
  const float* h     = (const float*)d_in[0];
  const float* coord = (const float*)d_in[1];
  const float* ln_g  = (const float*)d_in[2];
  const float* ln_b  = (const float*)d_in[3];
  const float* cW1   = (const float*)d_in[4];
  const float* cb1   = (const float*)d_in[5];
  const float* cW2   = (const float*)d_in[6];
  const float* cb2   = (const float*)d_in[7];
  const float* eW1   = (const float*)d_in[8];
  const float* eb1   = (const float*)d_in[9];
  const float* eW2   = (const float*)d_in[10];
  const float* eb2   = (const float*)d_in[11];
  const float* nW1   = (const float*)d_in[12];
  const float* nb1   = (const float*)d_in[13];
  const float* nW2   = (const float*)d_in[14];
  const float* nb2   = (const float*)d_in[15];

  char* ws = (char*)d_ws;
  short* WT   = (short*)(ws);                 // 1 MiB  (bf16 transposed weights)
  float* hnf  = (float*)(ws + (1u<<20));      // 1 MiB  hn fp32
  float* ABf  = (float*)(ws + (2u<<20));      // 2 MiB  A|B terms fp32 [2048][256]
  float* aggf = (float*)(ws + (4u<<20));      // 1 MiB  agg fp32
  float* hA   = (float*)(ws + (5u<<20));      // 1 MiB
  float* hB   = (float*)(ws + (6u<<20));      // 1 MiB

  k_wt<<<2048, 256, 0, stream>>>(cW2, eW1, eW2, nW1, nW2, WT);

  const float* hcur = h;
  for (int l=0;l<LL;l++){
    const short* WTl = WT + l*WT_LAYER;
    k_ln_ab<<<128, 256, 0, stream>>>(hcur, ln_g + l*HH, ln_b + l*HH, WTl, hnf, ABf);
    k_edge<<<256, 256, 0, stream>>>(coord, cW1 + l*2*HH, cb1 + l*HH, cb2 + l*HH,
                                    eb1 + l*HH, eb2 + l*HH, WTl, ABf, aggf);
    float* ho = (l==LL-1) ? (float*)d_out : ((l&1) ? hB : hA);
    k_node<<<128, 256, 0, stream>>>(hnf, aggf, nb1 + l*HH, nb2 + l*HH, WTl, ho);
    hcur = ho;
  }
}

// Round 3
// 368.843 us; speedup vs baseline: 1.5281x; 1.5281x over previous
//
#include <hip/hip_runtime.h>
#include <math.h>

#define NN 64
#define HH 128
#define LL 4

// WT layout (bf16 elements, per layer)
#define OFF_CW2T 0
#define OFF_W1AT 16384
#define OFF_W1BT 32768
#define OFF_W1CT 49152
#define OFF_EW2T 65536
#define OFF_NW2T 81920
#define OFF_NW1T 98304
#define WT_LAYER 131072

typedef short s8v __attribute__((ext_vector_type(8)));
typedef float f4v __attribute__((ext_vector_type(4)));

__device__ __forceinline__ short f2bf(float f){
  unsigned u = __float_as_uint(f);
  u += 0x7fffu + ((u>>16)&1u);
  return (short)(u>>16);
}
// branch-free erf-based GELU (A&S 7.1.26, max err 1.5e-7)
__device__ __forceinline__ float gelu(float x){
  float z = fabsf(x) * 0.70710678118654752f;
  float t = __builtin_amdgcn_rcpf(fmaf(0.3275911f, z, 1.0f));
  float p = fmaf(fmaf(fmaf(fmaf(1.061405429f, t, -1.453152027f), t,
                 1.421413741f), t, -0.284496736f), t, 0.254829592f) * t;
  float e = __expf(-z*z);
  float er = 1.0f - p*e;
  er = copysignf(er, x);
  return 0.5f*x*(1.0f+er);
}
__device__ __forceinline__ f4v mfma16(s8v a, s8v b, f4v c){
  return __builtin_amdgcn_mfma_f32_16x16x32_bf16(a,b,c,0,0,0);
}

// ---------------- kernel 0: transpose+convert all weights to bf16 [N][K] ----
__global__ __launch_bounds__(256) void k_wt(
  const float* __restrict__ cW2, const float* __restrict__ eW1,
  const float* __restrict__ eW2, const float* __restrict__ nW1,
  const float* __restrict__ nW2, short* __restrict__ WT)
{
  int gid = blockIdx.x*256 + threadIdx.x;   // 0 .. 524287
  int l = gid >> 17;
  int r = gid & 131071;
  float v;
  if (r < 32768 && r >= 16384){          // w1at
    int i = r-16384; int n = i>>7, k = i&127;
    v = eW1[l*49152 + k*128 + n];
  } else if (r < 16384){                 // cw2t
    int n = r>>7, k = r&127;
    v = cW2[l*16384 + k*128 + n];
  } else if (r < 49152){                 // w1bt
    int i = r-32768; int n = i>>7, k = i&127;
    v = eW1[l*49152 + (128+k)*128 + n];
  } else if (r < 65536){                 // w1ct
    int i = r-49152; int n = i>>7, k = i&127;
    v = eW1[l*49152 + (256+k)*128 + n];
  } else if (r < 81920){                 // ew2t
    int i = r-65536; int n = i>>7, k = i&127;
    v = eW2[l*16384 + k*128 + n];
  } else if (r < 98304){                 // nw2t
    int i = r-81920; int n = i>>7, k = i&127;
    v = nW2[l*16384 + k*128 + n];
  } else {                               // nw1t [128][256]
    int i = r-98304; int n = i>>8, k = i&255;
    v = nW1[l*32768 + k*128 + n];
  }
  WT[gid] = f2bf(v);
}

// ---------------- kernel 1: LayerNorm + AB precompute GEMM ------------------
__global__ __launch_bounds__(256) void k_ln_ab(
    const float* __restrict__ h,
    const float* __restrict__ lng, const float* __restrict__ lnb,
    const short* __restrict__ WT,
    float* __restrict__ hnf, float* __restrict__ ABf)
{
  __shared__ __align__(16) short hl[16*128];
  const int t = threadIdx.x;
  const int nl = t>>4, l16 = t&15;
  const int gn = blockIdx.x*16 + nl;
  const float* hp = h + gn*128 + l16*8;
  float4 f0 = *(const float4*)hp;
  float4 f1 = *(const float4*)(hp+4);
  float x[8] = {f0.x,f0.y,f0.z,f0.w,f1.x,f1.y,f1.z,f1.w};
  float s=0.f, sq=0.f;
  #pragma unroll
  for (int i=0;i<8;i++){ s += x[i]; sq += x[i]*x[i]; }
  #pragma unroll
  for (int m=1;m<16;m<<=1){ s += __shfl_xor(s,m,64); sq += __shfl_xor(sq,m,64); }
  float mu = s*(1.f/128.f);
  float var = sq*(1.f/128.f) - mu*mu;
  float rstd = rsqrtf(var + 1e-5f);
  s8v pk;
  float y[8];
  #pragma unroll
  for (int i=0;i<8;i++){
    int k = l16*8+i;
    y[i] = (x[i]-mu)*rstd*lng[k] + lnb[k];
    pk[i] = f2bf(y[i]);
  }
  float4 o0; o0.x=y[0];o0.y=y[1];o0.z=y[2];o0.w=y[3];
  float4 o1; o1.x=y[4];o1.y=y[5];o1.z=y[6];o1.w=y[7];
  *(float4*)(hnf + gn*128 + l16*8)     = o0;
  *(float4*)(hnf + gn*128 + l16*8 + 4) = o1;
  *(s8v*)&hl[nl*128 + ((l16 ^ (nl&7))<<3)] = pk;
  __syncthreads();

  const int w = t>>6, lane = t&63, q = lane>>4, c16 = lane&15;
  f4v acc[4];
  #pragma unroll
  for (int j=0;j<4;j++){
    #pragma unroll
    for (int e=0;e<4;e++) acc[j][e] = 0.f;
  }
  #pragma unroll
  for (int s4=0;s4<4;s4++){
    int kc = 4*s4+q;
    s8v a = *(const s8v*)&hl[c16*128 + ((kc ^ (c16&7))<<3)];
    #pragma unroll
    for (int j=0;j<4;j++){
      int cn = (w*4+j)*16 + c16;              // 0..255
      const short* bp = (cn < 128) ? (WT + OFF_W1AT + cn*128)
                                   : (WT + OFF_W1BT + (cn-128)*128);
      s8v bb = *(const s8v*)(bp + kc*8);
      acc[j] = mfma16(a, bb, acc[j]);
    }
  }
  #pragma unroll
  for (int j=0;j<4;j++){
    int cn = (w*4+j)*16 + c16;
    #pragma unroll
    for (int r=0;r<4;r++){
      ABf[(blockIdx.x*16 + 4*q + r)*256 + cn] = acc[j][r];
    }
  }
}

// ---------------- kernel 2: fused edge pipeline + aggregation ---------------
// One WG (512 thr, 8 waves) = (graph b, 8 rows). 8 chunks of 8 cols; M=64/chunk.
// Per wave: 1 m-tile (mt=w>>1) x 4 n-tiles (ntb=(w&1)*4).
__global__ __launch_bounds__(512, 2) void k_edge(
    const float* __restrict__ coord,
    const float* __restrict__ cW1l,
    const float* __restrict__ cb1g, const float* __restrict__ cb2g,
    const float* __restrict__ eb1g, const float* __restrict__ eb2g,
    const short* __restrict__ WT,
    const float* __restrict__ ABf,
    float* __restrict__ agg)
{
  __shared__ __align__(16) short Wc[2*128*128]; // [0]=cw2t [16384]=ew2t (swizzled)
  __shared__ __align__(16) short t0[64*128];
  __shared__ __align__(16) short t1[64*128];
  __shared__ __align__(16) float Atf[8*128];
  __shared__ __align__(16) float Btf[64*128];
  __shared__ __align__(16) float aggl[8*128];
  __shared__ float w1x[128], w1y[128], b1s[128], b2s[128], e1s[128], e2s[128];
  __shared__ float cxr[8], cyr[8], cxj[64], cyj[64];

  const int t = threadIdx.x;          // 0..511
  const int b  = blockIdx.x >> 3;
  const int rb = blockIdx.x & 7;
  const int gbase = b*NN;
  const int rows0 = gbase + rb*8;

  // stage swizzled weight matrices (cw2t, ew2t): 2048 s8v each
  #pragma unroll
  for (int i=0;i<4;i++){
    int idx16 = t + i*512;
    int n = idx16>>4, c = idx16&15;
    int dsw = n*128 + ((c ^ (n&7))<<3);
    *(s8v*)&Wc[dsw]          = *(const s8v*)(WT + OFF_CW2T + n*128 + c*8);
    *(s8v*)&Wc[16384 + dsw]  = *(const s8v*)(WT + OFF_EW2T + n*128 + c*8);
  }
  if (t < 128){
    w1x[t] = cW1l[t]; w1y[t] = cW1l[128+t];
    b1s[t] = cb1g[t]; b2s[t] = cb2g[t];
    e1s[t] = eb1g[t]; e2s[t] = eb2g[t];
  }
  if (t < 64){ cxj[t] = coord[(gbase+t)*2]; cyj[t] = coord[(gbase+t)*2+1]; }
  if (t >= 64 && t < 72){ int r=t-64; cxr[r] = coord[(rows0+r)*2]; cyr[r] = coord[(rows0+r)*2+1]; }
  // A-term rows (fp32): 256 float4
  if (t < 256){
    int r = t>>5, c = t&31;
    *(float4*)&Atf[r*128 + c*4] = *(const float4*)(ABf + (rows0+r)*256 + c*4);
  }
  // B-term cols (fp32): 2048 float4
  #pragma unroll
  for (int i=0;i<4;i++){
    int idx4 = t + i*512;
    int j = idx4>>5, c = idx4&31;
    *(float4*)&Btf[j*128 + c*4] = *(const float4*)(ABf + (gbase+j)*256 + 128 + c*4);
  }
  #pragma unroll
  for (int i=0;i<2;i++) aggl[t + i*512] = 0.f;

  const int w = t>>6, lane = t&63, q = lane>>4, c16 = lane&15;
  const int mt  = w>>1;          // 0..3
  const int ntb = (w&1)*4;       // n-tiles ntb..ntb+3

  // GEMM2 (W1c) B-fragments in registers, straight from global (linear)
  s8v wreg[4][4];
  #pragma unroll
  for (int j=0;j<4;j++){
    int n = (ntb+j)*16 + c16;
    #pragma unroll
    for (int s=0;s<4;s++)
      wreg[j][s] = *(const s8v*)(WT + OFF_W1CT + n*128 + (4*s+q)*8);
  }
  __syncthreads();

  const int row0 = mt*16 + c16;
  const int swz  = row0 & 7;

  for (int ch=0; ch<8; ch++){
    const int j0 = ch*8;
    // ---- Phase A: cd1 -> t0 ----
    {
      int m = t & 63;
      int r = m>>3, jj = m&7;
      float dx = cxr[r] - cxj[j0+jj];
      float dy = cyr[r] - cyj[j0+jj];
      int cb0 = t>>6;                // 0..7
      #pragma unroll
      for (int hf=0; hf<2; hf++){
        int kc = cb0 + hf*8;
        s8v pk;
        #pragma unroll
        for (int kk=0;kk<8;kk++){
          int k = kc*8+kk;
          pk[kk] = f2bf(gelu(fmaf(dx, w1x[k], fmaf(dy, w1y[k], b1s[k]))));
        }
        *(s8v*)&t0[m*128 + ((kc ^ (m&7))<<3)] = pk;
      }
    }
    __syncthreads();
    // ---- Phase B: t1 = gelu(t0 @ cW2 + cb2) ----
    {
      f4v acc[4];
      #pragma unroll
      for (int j=0;j<4;j++){
        #pragma unroll
        for (int e=0;e<4;e++) acc[j][e]=0.f;
      }
      #pragma unroll
      for (int s=0;s<4;s++){
        int kc = 4*s+q;
        s8v a0 = *(const s8v*)&t0[row0*128 + ((kc ^ swz)<<3)];
        #pragma unroll
        for (int j=0;j<4;j++){
          int n = (ntb+j)*16 + c16;
          s8v bb = *(const s8v*)&Wc[n*128 + ((kc ^ (n&7))<<3)];
          acc[j] = mfma16(a0, bb, acc[j]);
        }
      }
      #pragma unroll
      for (int j=0;j<4;j++){
        int cn = (ntb+j)*16 + c16;
        #pragma unroll
        for (int r=0;r<4;r++){
          int m = mt*16 + 4*q + r;
          float v = acc[j][r] + b2s[cn];
          t1[m*128 + (((cn>>3) ^ (m&7))<<3) + (cn&7)] = f2bf(gelu(v));
        }
      }
    }
    __syncthreads();
    // ---- Phase C: t0 = gelu(t1 @ W1c + A[i] + B[j] + eb1) ----
    {
      f4v acc[4];
      #pragma unroll
      for (int j=0;j<4;j++){
        #pragma unroll
        for (int e=0;e<4;e++) acc[j][e]=0.f;
      }
      #pragma unroll
      for (int s=0;s<4;s++){
        int kc = 4*s+q;
        s8v a0 = *(const s8v*)&t1[row0*128 + ((kc ^ swz)<<3)];
        #pragma unroll
        for (int j=0;j<4;j++)
          acc[j] = mfma16(a0, wreg[j][s], acc[j]);
      }
      #pragma unroll
      for (int j=0;j<4;j++){
        int cn = (ntb+j)*16 + c16;
        #pragma unroll
        for (int r=0;r<4;r++){
          int m = mt*16 + 4*q + r;
          int rr = m>>3, jj = m&7;
          float v = acc[j][r] + Atf[rr*128+cn] + Btf[(j0+jj)*128+cn] + e1s[cn];
          t0[m*128 + (((cn>>3) ^ (m&7))<<3) + (cn&7)] = f2bf(gelu(v));
        }
      }
    }
    __syncthreads();
    // ---- Phase D: ef2 = gelu(t0 @ eW2 + eb2); masked sum_j -> aggl ----
    {
      f4v acc[4];
      #pragma unroll
      for (int j=0;j<4;j++){
        #pragma unroll
        for (int e=0;e<4;e++) acc[j][e]=0.f;
      }
      #pragma unroll
      for (int s=0;s<4;s++){
        int kc = 4*s+q;
        s8v a0 = *(const s8v*)&t0[row0*128 + ((kc ^ swz)<<3)];
        #pragma unroll
        for (int j=0;j<4;j++){
          int n = (ntb+j)*16 + c16;
          s8v bb = *(const s8v*)&Wc[16384 + n*128 + ((kc ^ (n&7))<<3)];
          acc[j] = mfma16(a0, bb, acc[j]);
        }
      }
      #pragma unroll
      for (int j=0;j<4;j++){
        int cn = (ntb+j)*16 + c16;
        float s = 0.f;
        #pragma unroll
        for (int r=0;r<4;r++){
          int m = mt*16 + 4*q + r;
          float g = gelu(acc[j][r] + e2s[cn]);
          int rr = m>>3, jj = m&7;
          if (rb*8 + rr == j0 + jj) g = 0.f;   // no self-loop
          s += g;
        }
        s += __shfl_xor(s, 16, 64);
        if ((q&1)==0)
          aggl[(2*mt + (q>>1))*128 + cn] += s;
      }
    }
    __syncthreads();
  }
  #pragma unroll
  for (int i=0;i<2;i++){
    int idx = t + i*512;
    agg[(rows0 + (idx>>7))*128 + (idx&127)] = aggl[idx];
  }
}

// ---------------- kernel 3: node MLP + residual (last layer -> out) ---------
__global__ __launch_bounds__(256) void k_node(
    const float* __restrict__ hnf, const float* __restrict__ aggg,
    const float* __restrict__ nb1l, const float* __restrict__ nb2l,
    const short* __restrict__ WT,
    float* __restrict__ hout)
{
  __shared__ __align__(16) short cat[16*256];
  __shared__ __align__(16) short u1[16*128];
  __shared__ __align__(16) float hf[16*128];
  const int t = threadIdx.x;
  {
    const int row = t>>4, c = t&15;
    const int gn = blockIdx.x*16 + row;
    float4 f0 = *(const float4*)(hnf + gn*128 + c*8);
    float4 f1 = *(const float4*)(hnf + gn*128 + c*8 + 4);
    *(float4*)&hf[row*128 + c*8]     = f0;
    *(float4*)&hf[row*128 + c*8 + 4] = f1;
    s8v p;
    p[0]=f2bf(f0.x);p[1]=f2bf(f0.y);p[2]=f2bf(f0.z);p[3]=f2bf(f0.w);
    p[4]=f2bf(f1.x);p[5]=f2bf(f1.y);p[6]=f2bf(f1.z);p[7]=f2bf(f1.w);
    *(s8v*)&cat[row*256 + ((c ^ (row&7))<<3)] = p;
    float4 g0 = *(const float4*)(aggg + gn*128 + c*8);
    float4 g1 = *(const float4*)(aggg + gn*128 + c*8 + 4);
    s8v pg;
    pg[0]=f2bf(g0.x);pg[1]=f2bf(g0.y);pg[2]=f2bf(g0.z);pg[3]=f2bf(g0.w);
    pg[4]=f2bf(g1.x);pg[5]=f2bf(g1.y);pg[6]=f2bf(g1.z);pg[7]=f2bf(g1.w);
    *(s8v*)&cat[row*256 + (((16+c) ^ (row&7))<<3)] = pg;
  }
  __syncthreads();
  const int w = t>>6, lane = t&63, q = lane>>4, c16 = lane&15;
  f4v acc[2];
  #pragma unroll
  for (int j=0;j<2;j++){
    #pragma unroll
    for (int e=0;e<4;e++) acc[j][e]=0.f;
  }
  #pragma unroll
  for (int s=0;s<8;s++){
    int kc = 4*s+q;
    s8v a = *(const s8v*)&cat[c16*256 + ((kc ^ (c16&7))<<3)];
    #pragma unroll
    for (int j=0;j<2;j++){
      int cn = (w*2+j)*16 + c16;
      s8v bb = *(const s8v*)(WT + OFF_NW1T + cn*256 + kc*8);
      acc[j] = mfma16(a, bb, acc[j]);
    }
  }
  #pragma unroll
  for (int j=0;j<2;j++){
    int cn = (w*2+j)*16 + c16;
    #pragma unroll
    for (int r=0;r<4;r++){
      int m = 4*q+r;
      float v = acc[j][r] + nb1l[cn];
      u1[m*128 + (((cn>>3) ^ (m&7))<<3) + (cn&7)] = f2bf(gelu(v));
    }
  }
  __syncthreads();
  f4v acc2[2];
  #pragma unroll
  for (int j=0;j<2;j++){
    #pragma unroll
    for (int e=0;e<4;e++) acc2[j][e]=0.f;
  }
  #pragma unroll
  for (int s=0;s<4;s++){
    int kc = 4*s+q;
    s8v a = *(const s8v*)&u1[c16*128 + ((kc ^ (c16&7))<<3)];
    #pragma unroll
    for (int j=0;j<2;j++){
      int cn = (w*2+j)*16 + c16;
      s8v bb = *(const s8v*)(WT + OFF_NW2T + cn*128 + kc*8);
      acc2[j] = mfma16(a, bb, acc2[j]);
    }
  }
  #pragma unroll
  for (int j=0;j<2;j++){
    int cn = (w*2+j)*16 + c16;
    #pragma unroll
    for (int r=0;r<4;r++){
      int m = 4*q+r;
      hout[(blockIdx.x*16 + m)*128 + cn] = hf[m*128 + cn] + acc2[j][r] + nb2l[cn];
    }
  }
}

// -------- kernel 3b: node MLP + residual fused with next-layer LN+AB --------
__global__ __launch_bounds__(256) void k_node_ln(
    const float* hnf, const float* __restrict__ aggg,
    const float* __restrict__ nb1l, const float* __restrict__ nb2l,
    const short* __restrict__ WTl,
    const float* __restrict__ lng, const float* __restrict__ lnb,
    const short* __restrict__ WTn,
    float* hnf_out, float* __restrict__ ABf)
{
  __shared__ __align__(16) short cat[16*256];
  __shared__ __align__(16) short u1[16*128];
  __shared__ __align__(16) float hf[16*128];
  __shared__ __align__(16) float hnw[16*128];
  __shared__ __align__(16) short hl[16*128];
  const int t = threadIdx.x;
  {
    const int row = t>>4, c = t&15;
    const int gn = blockIdx.x*16 + row;
    float4 f0 = *(const float4*)(hnf + gn*128 + c*8);
    float4 f1 = *(const float4*)(hnf + gn*128 + c*8 + 4);
    *(float4*)&hf[row*128 + c*8]     = f0;
    *(float4*)&hf[row*128 + c*8 + 4] = f1;
    s8v p;
    p[0]=f2bf(f0.x);p[1]=f2bf(f0.y);p[2]=f2bf(f0.z);p[3]=f2bf(f0.w);
    p[4]=f2bf(f1.x);p[5]=f2bf(f1.y);p[6]=f2bf(f1.z);p[7]=f2bf(f1.w);
    *(s8v*)&cat[row*256 + ((c ^ (row&7))<<3)] = p;
    float4 g0 = *(const float4*)(aggg + gn*128 + c*8);
    float4 g1 = *(const float4*)(aggg + gn*128 + c*8 + 4);
    s8v pg;
    pg[0]=f2bf(g0.x);pg[1]=f2bf(g0.y);pg[2]=f2bf(g0.z);pg[3]=f2bf(g0.w);
    pg[4]=f2bf(g1.x);pg[5]=f2bf(g1.y);pg[6]=f2bf(g1.z);pg[7]=f2bf(g1.w);
    *(s8v*)&cat[row*256 + (((16+c) ^ (row&7))<<3)] = pg;
  }
  __syncthreads();
  const int w = t>>6, lane = t&63, q = lane>>4, c16 = lane&15;
  f4v acc[2];
  #pragma unroll
  for (int j=0;j<2;j++){
    #pragma unroll
    for (int e=0;e<4;e++) acc[j][e]=0.f;
  }
  #pragma unroll
  for (int s=0;s<8;s++){
    int kc = 4*s+q;
    s8v a = *(const s8v*)&cat[c16*256 + ((kc ^ (c16&7))<<3)];
    #pragma unroll
    for (int j=0;j<2;j++){
      int cn = (w*2+j)*16 + c16;
      s8v bb = *(const s8v*)(WTl + OFF_NW1T + cn*256 + kc*8);
      acc[j] = mfma16(a, bb, acc[j]);
    }
  }
  #pragma unroll
  for (int j=0;j<2;j++){
    int cn = (w*2+j)*16 + c16;
    #pragma unroll
    for (int r=0;r<4;r++){
      int m = 4*q+r;
      float v = acc[j][r] + nb1l[cn];
      u1[m*128 + (((cn>>3) ^ (m&7))<<3) + (cn&7)] = f2bf(gelu(v));
    }
  }
  __syncthreads();
  f4v acc2[2];
  #pragma unroll
  for (int j=0;j<2;j++){
    #pragma unroll
    for (int e=0;e<4;e++) acc2[j][e]=0.f;
  }
  #pragma unroll
  for (int s=0;s<4;s++){
    int kc = 4*s+q;
    s8v a = *(const s8v*)&u1[c16*128 + ((kc ^ (c16&7))<<3)];
    #pragma unroll
    for (int j=0;j<2;j++){
      int cn = (w*2+j)*16 + c16;
      s8v bb = *(const s8v*)(WTn ? (WTl + OFF_NW2T + cn*128 + kc*8)
                                 : (WTl + OFF_NW2T + cn*128 + kc*8));
      acc2[j] = mfma16(a, bb, acc2[j]);
    }
  }
  #pragma unroll
  for (int j=0;j<2;j++){
    int cn = (w*2+j)*16 + c16;
    #pragma unroll
    for (int r=0;r<4;r++){
      int m = 4*q+r;
      hnw[m*128 + cn] = hf[m*128 + cn] + acc2[j][r] + nb2l[cn];
    }
  }
  __syncthreads();
  // ---- LayerNorm (next layer) on hnw ----
  {
    const int nl = t>>4, l16 = t&15;
    const int gn = blockIdx.x*16 + nl;
    float x[8];
    #pragma unroll
    for (int i=0;i<8;i++) x[i] = hnw[nl*128 + l16*8 + i];
    float s=0.f, sq=0.f;
    #pragma unroll
    for (int i=0;i<8;i++){ s += x[i]; sq += x[i]*x[i]; }
    #pragma unroll
    for (int m=1;m<16;m<<=1){ s += __shfl_xor(s,m,64); sq += __shfl_xor(sq,m,64); }
    float mu = s*(1.f/128.f);
    float var = sq*(1.f/128.f) - mu*mu;
    float rstd = rsqrtf(var + 1e-5f);
    s8v pk;
    float y[8];
    #pragma unroll
    for (int i=0;i<8;i++){
      int k = l16*8+i;
      y[i] = (x[i]-mu)*rstd*lng[k] + lnb[k];
      pk[i] = f2bf(y[i]);
    }
    float4 o0; o0.x=y[0];o0.y=y[1];o0.z=y[2];o0.w=y[3];
    float4 o1; o1.x=y[4];o1.y=y[5];o1.z=y[6];o1.w=y[7];
    *(float4*)(hnf_out + gn*128 + l16*8)     = o0;
    *(float4*)(hnf_out + gn*128 + l16*8 + 4) = o1;
    *(s8v*)&hl[nl*128 + ((l16 ^ (nl&7))<<3)] = pk;
  }
  __syncthreads();
  // ---- AB GEMM (next layer) ----
  f4v accab[4];
  #pragma unroll
  for (int j=0;j<4;j++){
    #pragma unroll
    for (int e=0;e<4;e++) accab[j][e] = 0.f;
  }
  #pragma unroll
  for (int s4=0;s4<4;s4++){
    int kc = 4*s4+q;
    s8v a = *(const s8v*)&hl[c16*128 + ((kc ^ (c16&7))<<3)];
    #pragma unroll
    for (int j=0;j<4;j++){
      int cn = (w*4+j)*16 + c16;
      const short* bp = (cn < 128) ? (WTn + OFF_W1AT + cn*128)
                                   : (WTn + OFF_W1BT + (cn-128)*128);
      s8v bb = *(const s8v*)(bp + kc*8);
      accab[j] = mfma16(a, bb, accab[j]);
    }
  }
  #pragma unroll
  for (int j=0;j<4;j++){
    int cn = (w*4+j)*16 + c16;
    #pragma unroll
    for (int r=0;r<4;r++){
      ABf[(blockIdx.x*16 + 4*q + r)*256 + cn] = accab[j][r];
    }
  }
}

// ---------------- launch ----------------------------------------------------
extern "C" void kernel_launch(void* const* d_in, const int* in_sizes, int n_in,
                              void* d_out, int out_size, void* d_ws, size_t ws_size,
                              hipStream_t stream)
{
  (void)in_sizes; (void)n_in; (void)out_size; (void)ws_size;
  const float* h     = (const float*)d_in[0];
  const float* coord = (const float*)d_in[1];
  const float* ln_g  = (const float*)d_in[2];
  const float* ln_b  = (const float*)d_in[3];
  const float* cW1   = (const float*)d_in[4];
  const float* cb1   = (const float*)d_in[5];
  const float* cW2   = (const float*)d_in[6];
  const float* cb2   = (const float*)d_in[7];
  const float* eW1   = (const float*)d_in[8];
  const float* eb1   = (const float*)d_in[9];
  const float* eW2   = (const float*)d_in[10];
  const float* eb2   = (const float*)d_in[11];
  const float* nW1   = (const float*)d_in[12];
  const float* nb1   = (const float*)d_in[13];
  const float* nW2   = (const float*)d_in[14];
  const float* nb2   = (const float*)d_in[15];

  char* ws = (char*)d_ws;
  short* WT   = (short*)(ws);                 // 1 MiB  (bf16 transposed weights)
  float* hnf  = (float*)(ws + (1u<<20));      // 1 MiB  hn fp32
  float* ABf  = (float*)(ws + (2u<<20));      // 2 MiB  A|B terms fp32 [2048][256]
  float* aggf = (float*)(ws + (4u<<20));      // 1 MiB  agg fp32

  k_wt<<<2048, 256, 0, stream>>>(cW2, eW1, eW2, nW1, nW2, WT);
  k_ln_ab<<<128, 256, 0, stream>>>(h, ln_g, ln_b, WT, hnf, ABf);

  for (int l=0;l<LL;l++){
    const short* WTl = WT + l*WT_LAYER;
    k_edge<<<256, 512, 0, stream>>>(coord, cW1 + l*2*HH, cb1 + l*HH, cb2 + l*HH,
                                    eb1 + l*HH, eb2 + l*HH, WTl, ABf, aggf);
    if (l < LL-1){
      const short* WTn = WT + (l+1)*WT_LAYER;
      k_node_ln<<<128, 256, 0, stream>>>(hnf, aggf, nb1 + l*HH, nb2 + l*HH, WTl,
                                         ln_g + (l+1)*HH, ln_b + (l+1)*HH, WTn,
                                         hnf, ABf);
    } else {
      k_node<<<128, 256, 0, stream>>>(hnf, aggf, nb1 + l*HH, nb2 + l*HH, WTl,
                                      (float*)d_out);
    }
  }
}